// Round 3
// baseline (87.869 us; speedup 1.0000x reference)
//
#include <hip/hip_runtime.h>

#define BB 64
#define KK 4096
#define DD 512
#define HH 512

typedef __attribute__((ext_vector_type(8))) short bf16x8;
typedef __attribute__((ext_vector_type(4))) float f32x4;

// float -> bf16 bits, round-to-nearest-even
__device__ __forceinline__ unsigned short f2b(float f) {
  unsigned u = __float_as_uint(f);
  unsigned r = u + 0x7fffu + ((u >> 16) & 1u);
  return (unsigned short)(r >> 16);
}

// ---------------- K1: prep (3 independent parts keyed on blockIdx) ---------
// blocks [0,64):   qhT[h][b] = b1[h] + sum_d qemb[xq[b]][d] * W1[d][h]
// blocks [64,320): W1bT[h][d] = bf16(W1[D+d][h])   (32x32 LDS transpose)
// blocks [320,832): kembB = bf16(kemb)             (straight convert)
__global__ __launch_bounds__(256) void prep_kernel(
    const int* __restrict__ xq, const float* __restrict__ qemb,
    const float* __restrict__ W1, const float* __restrict__ b1,
    const float* __restrict__ kemb,
    float* __restrict__ qhT, unsigned short* __restrict__ W1bT,
    unsigned short* __restrict__ kembB) {
  const int bid = blockIdx.x, t = threadIdx.x;
  if (bid < 64) {
    __shared__ float qrow[DD];
    const int row = xq[bid];
    qrow[t]       = qemb[(long)row * DD + t];
    qrow[t + 256] = qemb[(long)row * DD + t + 256];
    __syncthreads();
    float a0 = b1[t], a1 = b1[t + 256];
    #pragma unroll 8
    for (int d = 0; d < DD; ++d) {
      const float qv = qrow[d];
      a0 = fmaf(qv, W1[d * HH + t], a0);
      a1 = fmaf(qv, W1[d * HH + t + 256], a1);
    }
    qhT[t * BB + bid]         = a0;
    qhT[(t + 256) * BB + bid] = a1;
  } else if (bid < 320) {
    __shared__ float tile[32][33];
    const int tb = bid - 64;
    const int d0 = (tb & 15) * 32, h0 = (tb >> 4) * 32;
    for (int i = t; i < 1024; i += 256) {
      int r = i >> 5, c = i & 31;                    // r: d, c: h
      tile[r][c] = W1[(DD + d0 + r) * HH + h0 + c];  // coalesced over h
    }
    __syncthreads();
    for (int i = t; i < 1024; i += 256) {
      int r = i >> 5, c = i & 31;                    // r: h, c: d
      W1bT[(h0 + r) * DD + d0 + c] = f2b(tile[c][r]);
    }
  } else {
    const long base = (long)(bid - 320) * 4096 + (long)t * 16;
    float4 f0 = *(const float4*)(kemb + base);
    float4 f1 = *(const float4*)(kemb + base + 4);
    float4 f2v = *(const float4*)(kemb + base + 8);
    float4 f3 = *(const float4*)(kemb + base + 12);
    bf16x8 o0, o1;
    o0[0] = (short)f2b(f0.x); o0[1] = (short)f2b(f0.y);
    o0[2] = (short)f2b(f0.z); o0[3] = (short)f2b(f0.w);
    o0[4] = (short)f2b(f1.x); o0[5] = (short)f2b(f1.y);
    o0[6] = (short)f2b(f1.z); o0[7] = (short)f2b(f1.w);
    o1[0] = (short)f2b(f2v.x); o1[1] = (short)f2b(f2v.y);
    o1[2] = (short)f2b(f2v.z); o1[3] = (short)f2b(f2v.w);
    o1[4] = (short)f2b(f3.x); o1[5] = (short)f2b(f3.y);
    o1[6] = (short)f2b(f3.z); o1[7] = (short)f2b(f3.w);
    *(bf16x8*)(kembB + base)     = o0;
    *(bf16x8*)(kembB + base + 8) = o1;
  }
}

// ---------------- K2: khT[h][k] = f32( sum_d W1b[d][h]*kemb[k][d] ), MFMA ---
// Wave tile 32h x 64k, block = 4 waves = 128h x 64k. Pure bf16x8 loads, no
// conversions in the loop. D layout: col=lane&15 (k), row=(lane>>4)*4+r (h).
__global__ __launch_bounds__(256) void khT_mfma_kernel(
    const unsigned short* __restrict__ kembB,
    const unsigned short* __restrict__ W1bT,
    float* __restrict__ khT) {
  const int t = threadIdx.x;
  const int l = t & 63, w = t >> 6;
  const int kb = blockIdx.x * 64;
  const int hb = blockIdx.y * 128 + w * 32;
  const int lm = l & 15, lg = l >> 4;
  f32x4 acc[2][4] = {};
  const unsigned short* ap = W1bT + (hb + lm) * DD + lg * 8;
  const unsigned short* bp = kembB + (long)(kb + lm) * DD + lg * 8;
  for (int d0 = 0; d0 < DD; d0 += 32) {
    bf16x8 a0 = *(const bf16x8*)(ap + d0);
    bf16x8 a1 = *(const bf16x8*)(ap + 16 * DD + d0);
    #pragma unroll
    for (int nt = 0; nt < 4; ++nt) {
      bf16x8 bb = *(const bf16x8*)(bp + (long)nt * 16 * DD + d0);
      acc[0][nt] = __builtin_amdgcn_mfma_f32_16x16x32_bf16(a0, bb, acc[0][nt], 0, 0, 0);
      acc[1][nt] = __builtin_amdgcn_mfma_f32_16x16x32_bf16(a1, bb, acc[1][nt], 0, 0, 0);
    }
  }
  #pragma unroll
  for (int mt = 0; mt < 2; ++mt)
    #pragma unroll
    for (int nt = 0; nt < 4; ++nt)
      #pragma unroll
      for (int r = 0; r < 4; ++r)
        khT[(long)(hb + mt * 16 + lg * 4 + r) * KK + kb + nt * 16 + lm] = acc[mt][nt][r];
}

// ---------------- K3: out[b][k] = b2 + sum_h relu(qhT[h][b]+khT[h][k])*w2[h]
// 512 blocks x 512 threads (4 waves/SIMD). Thread owns (b, 2 consecutive k,
// one h-half of 256). float2 math throughout; LDS reduce over the 2 halves.
__global__ __launch_bounds__(512) void logits3_kernel(
    const float* __restrict__ qhT, const float* __restrict__ khT,
    const float* __restrict__ w2, const float* __restrict__ b2,
    float* __restrict__ out) {
  __shared__ float w2s[HH];
  __shared__ float part[2][BB][8];
  const int t = threadIdx.x;
  const int kb = blockIdx.x * 8;
  w2s[t] = w2[t];
  __syncthreads();
  const int kg = t & 3, b = (t >> 2) & 63, hh = t >> 8;
  const float* qp = qhT + hh * 256 * BB + b;
  const float* kp = khT + (long)(hh * 256) * KK + kb + kg * 2;
  const float* wp = w2s + hh * 256;
  float2 acc = make_float2(0.f, 0.f);
  #pragma unroll 8
  for (int i = 0; i < 256; ++i) {
    const float q = qp[(long)i * BB];
    const float2 kv = *(const float2*)(kp + (long)i * KK);
    const float wv = wp[i];
    acc.x = fmaf(fmaxf(q + kv.x, 0.f), wv, acc.x);
    acc.y = fmaf(fmaxf(q + kv.y, 0.f), wv, acc.y);
  }
  part[hh][b][kg * 2]     = acc.x;
  part[hh][b][kg * 2 + 1] = acc.y;
  __syncthreads();
  if (t < 256) {
    const int bo = t >> 2, ko = t & 3;
    const float bias = b2[0];
    float2 p0 = *(const float2*)&part[0][bo][ko * 2];
    float2 p1 = *(const float2*)&part[1][bo][ko * 2];
    float2 r;
    r.x = p0.x + p1.x + bias;
    r.y = p0.y + p1.y + bias;
    *(float2*)(out + (long)bo * KK + kb + ko * 2) = r;
  }
}

extern "C" void kernel_launch(void* const* d_in, const int* in_sizes, int n_in,
                              void* d_out, int out_size, void* d_ws, size_t ws_size,
                              hipStream_t stream) {
  const int*   xq   = (const int*)d_in[0];
  const float* qemb = (const float*)d_in[1];
  const float* kemb = (const float*)d_in[2];
  const float* W1   = (const float*)d_in[3];
  const float* b1   = (const float*)d_in[4];
  const float* W2   = (const float*)d_in[5];
  const float* b2   = (const float*)d_in[6];
  float* out = (float*)d_out;

  float* qhT = (float*)d_ws;                                  // 128 KB
  float* khT = qhT + HH * BB;                                 // 8 MB (f32)
  unsigned short* W1bT  = (unsigned short*)(khT + (long)HH * KK);  // 512 KB
  unsigned short* kembB = W1bT + HH * DD;                     // 4 MB

  hipLaunchKernelGGL(prep_kernel, dim3(832), dim3(256), 0, stream,
                     xq, qemb, W1, b1, kemb, qhT, W1bT, kembB);
  hipLaunchKernelGGL(khT_mfma_kernel, dim3(KK / 64, HH / 128), dim3(256), 0, stream,
                     kembB, W1bT, khT);
  hipLaunchKernelGGL(logits3_kernel, dim3(KK / 8), dim3(512), 0, stream,
                     qhT, khT, W2, b2, out);
}

// Round 5
// 72.793 us; speedup vs baseline: 1.2071x; 1.2071x over previous
//
#include <hip/hip_runtime.h>

#define BB 64
#define KK 4096
#define DD 512
#define HH 512

typedef __attribute__((ext_vector_type(8))) short bf16x8;
typedef __attribute__((ext_vector_type(4))) float f32x4;

// float -> bf16 bits, round-to-nearest-even
__device__ __forceinline__ unsigned short f2b(float f) {
  unsigned u = __float_as_uint(f);
  unsigned r = u + 0x7fffu + ((u >> 16) & 1u);
  return (unsigned short)(r >> 16);
}

// Packed fragment layouts (chunk = 512 shorts = [64 lanes][8 bf16], 1KB):
//   W1p[ht][dt]: lane l holds W1b[d = dt*32 + (l>>4)*8 + j][h = ht*16 + (l&15)]
//   kp [kt][dt]: lane l holds kemb[k = kt*16 + (l&15)][d = dt*32 + (l>>4)*8 + j]
// A wave's MFMA fragment load = one contiguous 1KB read.

// ---------------- K1: prep --------------------------------------------------
// blocks [0,64):    qhT[h][b] = b1[h] + sum_d qemb[xq[b]][d] * W1[d][h]
// blocks [64,320):  W1p packed-bf16 of W1[D:,:]   (LDS transpose + pack)
// blocks [320,832): kp packed-bf16 of kemb
__global__ __launch_bounds__(256) void prep_kernel(
    const int* __restrict__ xq, const float* __restrict__ qemb,
    const float* __restrict__ W1, const float* __restrict__ b1,
    const float* __restrict__ kemb,
    float* __restrict__ qhT, unsigned short* __restrict__ W1p,
    unsigned short* __restrict__ kp) {
  const int bid = blockIdx.x, t = threadIdx.x;
  if (bid < 64) {
    __shared__ float qrow[DD];
    const int row = xq[bid];
    qrow[t]       = qemb[(long)row * DD + t];
    qrow[t + 256] = qemb[(long)row * DD + t + 256];
    __syncthreads();
    float a0 = b1[t], a1 = b1[t + 256];
    #pragma unroll 8
    for (int d = 0; d < DD; ++d) {
      const float qv = qrow[d];
      a0 = fmaf(qv, W1[d * HH + t], a0);
      a1 = fmaf(qv, W1[d * HH + t + 256], a1);
    }
    qhT[t * BB + bid]         = a0;
    qhT[(t + 256) * BB + bid] = a1;
  } else if (bid < 320) {
    __shared__ float tile[32][33];       // [d_local][h_local]
    const int tb = bid - 64;
    const int d0 = (tb & 15) * 32, h0 = (tb >> 4) * 32;
    for (int i = t; i < 1024; i += 256) {
      int r = i >> 5, c = i & 31;
      tile[r][c] = W1[(DD + d0 + r) * HH + h0 + c];   // coalesced over h
    }
    __syncthreads();
    // emit 2 chunks (ht = h0/16 + {0,1}, dt = d0/32), 1024 shorts, 4/thread
    const int i = t * 4;
    const int ci = i >> 9, li = i & 511;
    const int l = li >> 3, j0 = li & 7;
    const int ht = (h0 >> 4) + ci, dt = d0 >> 5;
    ushort4 o;
    o.x = f2b(tile[(l >> 4) * 8 + j0 + 0][ci * 16 + (l & 15)]);
    o.y = f2b(tile[(l >> 4) * 8 + j0 + 1][ci * 16 + (l & 15)]);
    o.z = f2b(tile[(l >> 4) * 8 + j0 + 2][ci * 16 + (l & 15)]);
    o.w = f2b(tile[(l >> 4) * 8 + j0 + 3][ci * 16 + (l & 15)]);
    *(ushort4*)(W1p + (ht * 16 + dt) * 512 + li) = o;
  } else {
    // pack kemb: 262144 lane-tasks, 2 per thread
    #pragma unroll
    for (int rep = 0; rep < 2; ++rep) {
      const int tt = (bid - 320) * 512 + t * 2 + rep;
      const int chunk = tt >> 6, l = tt & 63;
      const int kt = chunk >> 4, dt = chunk & 15;
      const int k = kt * 16 + (l & 15);
      const int d = dt * 32 + (l >> 4) * 8;
      const float4 f0 = *(const float4*)(kemb + (long)k * DD + d);
      const float4 f1 = *(const float4*)(kemb + (long)k * DD + d + 4);
      bf16x8 o;
      o[0] = (short)f2b(f0.x); o[1] = (short)f2b(f0.y);
      o[2] = (short)f2b(f0.z); o[3] = (short)f2b(f0.w);
      o[4] = (short)f2b(f1.x); o[5] = (short)f2b(f1.y);
      o[6] = (short)f2b(f1.z); o[7] = (short)f2b(f1.w);
      *(bf16x8*)(kp + (long)chunk * 512 + l * 8) = o;
    }
  }
}

// ---------------- K2: khT[h][k] = f32 GEMM via packed fragments -------------
// Wave tile 32h x 32k (2x2 chunks); block 4 waves = 64h x 64k; grid (64, 8).
// All fragment loads are contiguous 1KB per wave.
__global__ __launch_bounds__(256) void khT_mfma2_kernel(
    const unsigned short* __restrict__ kp,
    const unsigned short* __restrict__ W1p,
    float* __restrict__ khT) {
  const int t = threadIdx.x;
  const int l = t & 63, w = t >> 6;
  const int kt0 = blockIdx.x * 4 + (w & 1) * 2;   // chunk units (16 k each)
  const int ht0 = blockIdx.y * 4 + (w >> 1) * 2;  // chunk units (16 h each)
  const unsigned short* ap = W1p + (long)ht0 * 16 * 512 + l * 8;
  const unsigned short* bp = kp + (long)kt0 * 16 * 512 + l * 8;
  f32x4 acc[2][2] = {};
  #pragma unroll 4
  for (int dt = 0; dt < 16; ++dt) {
    bf16x8 a0 = *(const bf16x8*)(ap + dt * 512);
    bf16x8 a1 = *(const bf16x8*)(ap + (16 + dt) * 512);
    bf16x8 b0 = *(const bf16x8*)(bp + dt * 512);
    bf16x8 b1 = *(const bf16x8*)(bp + (16 + dt) * 512);
    acc[0][0] = __builtin_amdgcn_mfma_f32_16x16x32_bf16(a0, b0, acc[0][0], 0, 0, 0);
    acc[0][1] = __builtin_amdgcn_mfma_f32_16x16x32_bf16(a0, b1, acc[0][1], 0, 0, 0);
    acc[1][0] = __builtin_amdgcn_mfma_f32_16x16x32_bf16(a1, b0, acc[1][0], 0, 0, 0);
    acc[1][1] = __builtin_amdgcn_mfma_f32_16x16x32_bf16(a1, b1, acc[1][1], 0, 0, 0);
  }
  const int lm = l & 15, lg = l >> 4;
  #pragma unroll
  for (int mt = 0; mt < 2; ++mt)
    #pragma unroll
    for (int nt = 0; nt < 2; ++nt)
      #pragma unroll
      for (int r = 0; r < 4; ++r)
        khT[(long)((ht0 + mt) * 16 + lg * 4 + r) * KK + (kt0 + nt) * 16 + lm] =
            acc[mt][nt][r];
}

// ---------------- K3: partial relu-dot over h-slices ------------------------
// grid (64 kt, 8 hs), 256 thr. Thread: 4b x 4k accs, 64 h iters.
// part[hs][b][k] = sum_{h in slice} relu(qhT[h][b]+khT[h][k]) * w2[h]
__global__ __launch_bounds__(256) void logits4_kernel(
    const float* __restrict__ qhT, const float* __restrict__ khT,
    const float* __restrict__ w2, float* __restrict__ part) {
  const int t = threadIdx.x;
  const int kb = blockIdx.x * 64;
  const int h0 = blockIdx.y * 64;
  const int kq = t & 15, bq = t >> 4;
  const float* kpr = khT + (long)h0 * KK + kb + kq * 4;
  const float* qpr = qhT + (long)h0 * BB + bq * 4;
  const float* wpr = w2 + h0;
  float acc[4][4] = {};
  #pragma unroll 4
  for (int i = 0; i < 64; ++i) {
    const float4 kv = *(const float4*)(kpr + (long)i * KK);
    const float4 qv = *(const float4*)(qpr + (long)i * BB);
    const float wv = wpr[i];
    const float kk[4] = {kv.x, kv.y, kv.z, kv.w};
    const float qq[4] = {qv.x, qv.y, qv.z, qv.w};
    #pragma unroll
    for (int jb = 0; jb < 4; ++jb)
      #pragma unroll
      for (int jk = 0; jk < 4; ++jk)
        acc[jb][jk] = fmaf(fmaxf(qq[jb] + kk[jk], 0.f), wv, acc[jb][jk]);
  }
  #pragma unroll
  for (int jb = 0; jb < 4; ++jb) {
    float4 cv = make_float4(acc[jb][0], acc[jb][1], acc[jb][2], acc[jb][3]);
    *(float4*)(part + (long)(blockIdx.y * BB + bq * 4 + jb) * KK + kb + kq * 4) = cv;
  }
}

// ---------------- K4: out[b][k] = b2 + sum_hs part[hs][b][k] ---------------
__global__ __launch_bounds__(256) void reduce_kernel(
    const float* __restrict__ part, const float* __restrict__ b2,
    float* __restrict__ out) {
  const int tid = blockIdx.x * 256 + threadIdx.x;   // 65536 float4 tasks
  const int b = tid >> 10, kq = tid & 1023;
  const float bias = b2[0];
  float4 s = make_float4(bias, bias, bias, bias);
  #pragma unroll
  for (int hs = 0; hs < 8; ++hs) {
    const float4 p = *(const float4*)(part + (long)(hs * BB + b) * KK + kq * 4);
    s.x += p.x; s.y += p.y; s.z += p.z; s.w += p.w;
  }
  *(float4*)(out + (long)b * KK + kq * 4) = s;
}

extern "C" void kernel_launch(void* const* d_in, const int* in_sizes, int n_in,
                              void* d_out, int out_size, void* d_ws, size_t ws_size,
                              hipStream_t stream) {
  const int*   xq   = (const int*)d_in[0];
  const float* qemb = (const float*)d_in[1];
  const float* kemb = (const float*)d_in[2];
  const float* W1   = (const float*)d_in[3];
  const float* b1   = (const float*)d_in[4];
  const float* W2   = (const float*)d_in[5];
  const float* b2   = (const float*)d_in[6];
  float* out = (float*)d_out;

  float* qhT = (float*)d_ws;                                   // 128 KB
  float* khT = qhT + HH * BB;                                  // 8 MB
  float* part = khT + (long)HH * KK;                           // 8 MB
  unsigned short* W1p = (unsigned short*)(part + (long)8 * BB * KK); // 512 KB
  unsigned short* kp  = W1p + HH * DD;                         // 4 MB

  hipLaunchKernelGGL(prep_kernel, dim3(832), dim3(256), 0, stream,
                     xq, qemb, W1, b1, kemb, qhT, W1p, kp);
  hipLaunchKernelGGL(khT_mfma2_kernel, dim3(KK / 64, HH / 64), dim3(256), 0, stream,
                     kp, W1p, khT);
  hipLaunchKernelGGL(logits4_kernel, dim3(64, 8), dim3(256), 0, stream,
                     qhT, khT, W2, part);
  hipLaunchKernelGGL(reduce_kernel, dim3(256), dim3(256), 0, stream,
                     part, b2, out);
}

// Round 6
// 37.627 us; speedup vs baseline: 2.3352x; 1.9346x over previous
//
#include <hip/hip_runtime.h>

#define BB 64
#define KK 4096
#define DD 512
#define HH 512

typedef __attribute__((ext_vector_type(8))) short bf16x8;
typedef __attribute__((ext_vector_type(4))) float f32x4;

// float -> bf16 bits, round-to-nearest-even
__device__ __forceinline__ unsigned short f2b(float f) {
  unsigned u = __float_as_uint(f);
  unsigned r = u + 0x7fffu + ((u >> 16) & 1u);
  return (unsigned short)(r >> 16);
}

// Fragment chunk = 512 shorts = [64 lanes][8 bf16] = 1KB, coalesced per wave.
//  qp [c = bt*16+dt]:  lane l: q[bt*16+(l&15)][dt*32+(l>>4)*8+j]   (bt<4, dt<16)
//  W1p[c = ht*32+dtg]: lane l: W1[dtg*32+(l>>4)*8+j][ht*16+(l&15)] (ht<32, dtg<32)
//  kp [c = kt*16+dt]:  lane l: kemb[kt*16+(l&15)][dt*32+(l>>4)*8+j] (kt<256, dt<16)
// mfma(A=W1p-frag, B=data-frag): D row(M)=h=(l>>4)*4+r, col(N)=l&15.

// ---------------- K1: prep (pack everything) --------------------------------
// blocks [0,16):      pack q (gather via xq)     : 64 chunks, 1 per wave
// blocks [16,528):    pack W1 full (both halves) : 32x32 LDS transpose tiles
// blocks [528,1040):  pack kemb
__global__ __launch_bounds__(256) void prep_kernel(
    const int* __restrict__ xq, const float* __restrict__ qemb,
    const float* __restrict__ W1, const float* __restrict__ kemb,
    unsigned short* __restrict__ qp, unsigned short* __restrict__ W1p,
    unsigned short* __restrict__ kp) {
  const int bid = blockIdx.x, t = threadIdx.x;
  if (bid < 16) {
    const int w = t >> 6, l = t & 63;
    const int chunk = bid * 4 + w;           // 0..63
    const int bt = chunk >> 4, dt = chunk & 15;
    const int brow = bt * 16 + (l & 15);
    const int row = xq[brow];
    const int d = dt * 32 + (l >> 4) * 8;
    const float4 f0 = *(const float4*)(qemb + (long)row * DD + d);
    const float4 f1 = *(const float4*)(qemb + (long)row * DD + d + 4);
    bf16x8 o;
    o[0] = (short)f2b(f0.x); o[1] = (short)f2b(f0.y);
    o[2] = (short)f2b(f0.z); o[3] = (short)f2b(f0.w);
    o[4] = (short)f2b(f1.x); o[5] = (short)f2b(f1.y);
    o[6] = (short)f2b(f1.z); o[7] = (short)f2b(f1.w);
    *(bf16x8*)(qp + chunk * 512 + l * 8) = o;
  } else if (bid < 528) {
    __shared__ float tile[32][33];           // [d_local][h_local]
    const int tb = bid - 16;                 // 0..511
    const int d0 = (tb & 31) * 32;           // 0..1023 (full W1)
    const int h0 = (tb >> 5) * 32;           // 0..511
    for (int i = t; i < 1024; i += 256) {
      int r = i >> 5, c = i & 31;
      tile[r][c] = W1[(long)(d0 + r) * HH + h0 + c];   // coalesced over h
    }
    __syncthreads();
    const int i = t * 4;
    const int ci = i >> 9, li = i & 511;
    const int l = li >> 3, j0 = li & 7;      // j0 in {0,4}
    ushort4 o;
    o.x = f2b(tile[(l >> 4) * 8 + j0 + 0][ci * 16 + (l & 15)]);
    o.y = f2b(tile[(l >> 4) * 8 + j0 + 1][ci * 16 + (l & 15)]);
    o.z = f2b(tile[(l >> 4) * 8 + j0 + 2][ci * 16 + (l & 15)]);
    o.w = f2b(tile[(l >> 4) * 8 + j0 + 3][ci * 16 + (l & 15)]);
    const int cglob = ((tb >> 5) * 2 + ci) * 32 + (tb & 31);
    *(ushort4*)(W1p + cglob * 512 + li) = o;
  } else {
    #pragma unroll
    for (int rep = 0; rep < 2; ++rep) {
      const int tt = (bid - 528) * 512 + t * 2 + rep;
      const int chunk = tt >> 6, l = tt & 63;
      const int kt = chunk >> 4, dt = chunk & 15;
      const int k = kt * 16 + (l & 15);
      const int d = dt * 32 + (l >> 4) * 8;
      const float4 f0 = *(const float4*)(kemb + (long)k * DD + d);
      const float4 f1 = *(const float4*)(kemb + (long)k * DD + d + 4);
      bf16x8 o;
      o[0] = (short)f2b(f0.x); o[1] = (short)f2b(f0.y);
      o[2] = (short)f2b(f0.z); o[3] = (short)f2b(f0.w);
      o[4] = (short)f2b(f1.x); o[5] = (short)f2b(f1.y);
      o[6] = (short)f2b(f1.z); o[7] = (short)f2b(f1.w);
      *(bf16x8*)(kp + (long)chunk * 512 + l * 8) = o;
    }
  }
}

// ---------------- K2: qhT[h][b] = b1[h] + (q @ W1a)^T via MFMA --------------
// grid 32 (= ht), 4 waves (= bt). 16 dt-steps, A = W1p dtg 0..15, B = qp.
__global__ __launch_bounds__(256) void qh_mfma_kernel(
    const unsigned short* __restrict__ qp,
    const unsigned short* __restrict__ W1p,
    const float* __restrict__ b1, float* __restrict__ qhT) {
  const int t = threadIdx.x;
  const int w = t >> 6, l = t & 63;
  const int ht = blockIdx.x;
  const unsigned short* ap = W1p + (ht * 32) * 512 + l * 8;   // dtg 0..15
  const unsigned short* bp = qp + (w * 16) * 512 + l * 8;
  f32x4 acc = {};
  #pragma unroll
  for (int dt = 0; dt < 16; ++dt) {
    bf16x8 a = *(const bf16x8*)(ap + dt * 512);
    bf16x8 b = *(const bf16x8*)(bp + dt * 512);
    acc = __builtin_amdgcn_mfma_f32_16x16x32_bf16(a, b, acc, 0, 0, 0);
  }
  const int lm = l & 15, lg = l >> 4;
  const float4 bv = *(const float4*)(b1 + ht * 16 + lg * 4);
  const float bb[4] = {bv.x, bv.y, bv.z, bv.w};
  #pragma unroll
  for (int r = 0; r < 4; ++r)
    qhT[(ht * 16 + lg * 4 + r) * BB + w * 16 + lm] = acc[r] + bb[r];
}

// ---------------- K3: khT[h][k] f32 GEMM via packed fragments ---------------
// Wave tile 32h x 32k; block 4 waves = 64h x 64k; grid (64, 8).
__global__ __launch_bounds__(256) void khT_mfma_kernel(
    const unsigned short* __restrict__ kp,
    const unsigned short* __restrict__ W1p,
    float* __restrict__ khT) {
  const int t = threadIdx.x;
  const int l = t & 63, w = t >> 6;
  const int kt0 = blockIdx.x * 4 + (w & 1) * 2;   // chunk units (16 k)
  const int ht0 = blockIdx.y * 4 + (w >> 1) * 2;  // chunk units (16 h)
  const unsigned short* ap = W1p + (long)(ht0 * 32 + 16) * 512 + l * 8; // dtg 16..31
  const unsigned short* bp = kp + (long)(kt0 * 16) * 512 + l * 8;
  f32x4 acc[2][2] = {};
  #pragma unroll 4
  for (int dt = 0; dt < 16; ++dt) {
    bf16x8 a0 = *(const bf16x8*)(ap + dt * 512);
    bf16x8 a1 = *(const bf16x8*)(ap + 32 * 512 + dt * 512);
    bf16x8 b0 = *(const bf16x8*)(bp + dt * 512);
    bf16x8 b1 = *(const bf16x8*)(bp + 16 * 512 + dt * 512);
    acc[0][0] = __builtin_amdgcn_mfma_f32_16x16x32_bf16(a0, b0, acc[0][0], 0, 0, 0);
    acc[0][1] = __builtin_amdgcn_mfma_f32_16x16x32_bf16(a0, b1, acc[0][1], 0, 0, 0);
    acc[1][0] = __builtin_amdgcn_mfma_f32_16x16x32_bf16(a1, b0, acc[1][0], 0, 0, 0);
    acc[1][1] = __builtin_amdgcn_mfma_f32_16x16x32_bf16(a1, b1, acc[1][1], 0, 0, 0);
  }
  const int lm = l & 15, lg = l >> 4;
  #pragma unroll
  for (int mt = 0; mt < 2; ++mt)
    #pragma unroll
    for (int nt = 0; nt < 2; ++nt)
      #pragma unroll
      for (int r = 0; r < 4; ++r)
        khT[(long)((ht0 + mt) * 16 + lg * 4 + r) * KK + (kt0 + nt) * 16 + lm] =
            acc[mt][nt][r];
}

// ---------------- K4: partial relu-dot --------------------------------------
// grid (64 kb, 8 hs) x 512 thr (4 waves/SIMD). hs-slice = 64 h, split in two
// 32-h halves across thread groups; LDS-combined before the part store.
__global__ __launch_bounds__(512) void logits5_kernel(
    const float* __restrict__ qhT, const float* __restrict__ khT,
    const float* __restrict__ w2, float* __restrict__ part) {
  __shared__ float qs[64][68];
  __shared__ float w2s[64];
  __shared__ float pstage[16 * 16 * 16];
  const int t = threadIdx.x;
  const int kb = blockIdx.x * 64;
  const int hbase = blockIdx.y * 64;
  for (int task = t; task < 1024; task += 512) {
    const int h = task >> 4, b4 = (task & 15) * 4;
    *(float4*)&qs[h][b4] = *(const float4*)(qhT + (hbase + h) * BB + b4);
  }
  if (t < 64) w2s[t] = w2[hbase + t];
  __syncthreads();
  const int kq = t & 15, bq = (t >> 4) & 15, hh = t >> 8;
  const int h0 = hh * 32;
  const float* kvp = khT + (long)(hbase + h0) * KK + kb + kq * 4;
  float acc[4][4] = {};
  #pragma unroll 4
  for (int i = 0; i < 32; ++i) {
    const float4 kv = *(const float4*)(kvp + (long)i * KK);
    const float4 q4 = *(const float4*)&qs[h0 + i][bq * 4];
    const float wv = w2s[h0 + i];
    const float kk[4] = {kv.x, kv.y, kv.z, kv.w};
    const float qq[4] = {q4.x, q4.y, q4.z, q4.w};
    #pragma unroll
    for (int jb = 0; jb < 4; ++jb)
      #pragma unroll
      for (int jk = 0; jk < 4; ++jk)
        acc[jb][jk] = fmaf(fmaxf(qq[jb] + kk[jk], 0.f), wv, acc[jb][jk]);
  }
  if (hh == 1) {
    #pragma unroll
    for (int jb = 0; jb < 4; ++jb)
      #pragma unroll
      for (int jk = 0; jk < 4; ++jk)
        pstage[(bq * 16 + kq) * 16 + jb * 4 + jk] = acc[jb][jk];
  }
  __syncthreads();
  if (hh == 0) {
    #pragma unroll
    for (int jb = 0; jb < 4; ++jb) {
      float4 cv;
      cv.x = acc[jb][0] + pstage[(bq * 16 + kq) * 16 + jb * 4 + 0];
      cv.y = acc[jb][1] + pstage[(bq * 16 + kq) * 16 + jb * 4 + 1];
      cv.z = acc[jb][2] + pstage[(bq * 16 + kq) * 16 + jb * 4 + 2];
      cv.w = acc[jb][3] + pstage[(bq * 16 + kq) * 16 + jb * 4 + 3];
      *(float4*)(part + (long)(blockIdx.y * BB + bq * 4 + jb) * KK + kb + kq * 4) = cv;
    }
  }
}

// ---------------- K5: out[b][k] = b2 + sum_hs part[hs][b][k] ----------------
__global__ __launch_bounds__(256) void reduce_kernel(
    const float* __restrict__ part, const float* __restrict__ b2,
    float* __restrict__ out) {
  const int tid = blockIdx.x * 256 + threadIdx.x;   // 65536 float4 tasks
  const int b = tid >> 10, kq = tid & 1023;
  const float bias = b2[0];
  float4 s = make_float4(bias, bias, bias, bias);
  #pragma unroll
  for (int hs = 0; hs < 8; ++hs) {
    const float4 p = *(const float4*)(part + (long)(hs * BB + b) * KK + kq * 4);
    s.x += p.x; s.y += p.y; s.z += p.z; s.w += p.w;
  }
  *(float4*)(out + (long)b * KK + kq * 4) = s;
}

extern "C" void kernel_launch(void* const* d_in, const int* in_sizes, int n_in,
                              void* d_out, int out_size, void* d_ws, size_t ws_size,
                              hipStream_t stream) {
  const int*   xq   = (const int*)d_in[0];
  const float* qemb = (const float*)d_in[1];
  const float* kemb = (const float*)d_in[2];
  const float* W1   = (const float*)d_in[3];
  const float* b1   = (const float*)d_in[4];
  const float* W2   = (const float*)d_in[5];
  const float* b2   = (const float*)d_in[6];
  float* out = (float*)d_out;

  float* qhT  = (float*)d_ws;                         // 128 KB
  float* khT  = qhT + HH * BB;                        // 8 MB
  float* part = khT + (long)HH * KK;                  // 8 MB (8 slices)
  unsigned short* qp  = (unsigned short*)(part + (long)8 * BB * KK); // 64 KB
  unsigned short* W1p = qp + BB * DD;                 // 1 MB (full W1)
  unsigned short* kp  = W1p + 32 * 32 * 512;          // 4 MB

  hipLaunchKernelGGL(prep_kernel, dim3(1040), dim3(256), 0, stream,
                     xq, qemb, W1, kemb, qp, W1p, kp);
  hipLaunchKernelGGL(qh_mfma_kernel, dim3(32), dim3(256), 0, stream,
                     qp, W1p, b1, qhT);
  hipLaunchKernelGGL(khT_mfma_kernel, dim3(KK / 64, HH / 64), dim3(256), 0, stream,
                     kp, W1p, khT);
  hipLaunchKernelGGL(logits5_kernel, dim3(KK / 64, 8), dim3(512), 0, stream,
                     qhT, khT, W2, part);
  hipLaunchKernelGGL(reduce_kernel, dim3(256), dim3(256), 0, stream,
                     part, b2, out);
}